// Round 1
// baseline (1281.293 us; speedup 1.0000x reference)
//
#include <hip/hip_runtime.h>
#include <hip/hip_bf16.h>

typedef unsigned short u16;
typedef short bf16x8 __attribute__((ext_vector_type(8)));
typedef float f32x4 __attribute__((ext_vector_type(4)));

#define T_DIM 2048
#define C_DIM 2048
#define F_DIM 8192

// ---------- helpers ----------
__device__ __forceinline__ u16 f2bf(float f) {
    unsigned int u = __float_as_uint(f);
    u += 0x7fff + ((u >> 16) & 1);          // round-to-nearest-even
    return (u16)(u >> 16);
}

__device__ __forceinline__ void async16(const void* g, void* l) {
    __builtin_amdgcn_global_load_lds(
        (__attribute__((address_space(1))) const unsigned int*)g,
        (__attribute__((address_space(3))) unsigned int*)l, 16, 0, 0);
}

// ---------- LayerNorm (one block per row, C=2048) ----------
__global__ __launch_bounds__(256) void ln_row(const float* __restrict__ x,
                                              const float* __restrict__ w,
                                              const float* __restrict__ b,
                                              float* __restrict__ out) {
    __shared__ float red[8];
    const int t = blockIdx.x, tid = threadIdx.x;
    const float4* xr = (const float4*)(x + (size_t)t * C_DIM);
    float4 a0 = xr[tid * 2], a1 = xr[tid * 2 + 1];
    float s = a0.x + a0.y + a0.z + a0.w + a1.x + a1.y + a1.z + a1.w;
    float q = a0.x * a0.x + a0.y * a0.y + a0.z * a0.z + a0.w * a0.w
            + a1.x * a1.x + a1.y * a1.y + a1.z * a1.z + a1.w * a1.w;
    #pragma unroll
    for (int off = 32; off > 0; off >>= 1) {
        s += __shfl_down(s, off);
        q += __shfl_down(q, off);
    }
    const int lane = tid & 63, wv = tid >> 6;
    if (lane == 0) { red[wv] = s; red[4 + wv] = q; }
    __syncthreads();
    if (tid == 0) {
        red[0] = red[0] + red[1] + red[2] + red[3];
        red[4] = red[4] + red[5] + red[6] + red[7];
    }
    __syncthreads();
    s = red[0]; q = red[4];
    const float mean = s * (1.f / C_DIM);
    const float var = q * (1.f / C_DIM) - mean * mean;
    const float inv = rsqrtf(var + 1e-5f);
    const float4* w4 = (const float4*)w;
    const float4* b4 = (const float4*)b;
    float4* o4 = (float4*)(out + (size_t)t * C_DIM);
    #pragma unroll
    for (int j = 0; j < 2; ++j) {
        float4 xv = j ? a1 : a0;
        float4 wv4 = w4[tid * 2 + j], bv = b4[tid * 2 + j];
        float4 r;
        r.x = (xv.x - mean) * inv * wv4.x + bv.x;
        r.y = (xv.y - mean) * inv * wv4.y + bv.y;
        r.z = (xv.z - mean) * inv * wv4.z + bv.z;
        r.w = (xv.w - mean) * inv * wv4.w + bv.w;
        o4[tid * 2 + j] = r;
    }
}

// ---------- token-shift mixes ----------
__device__ __forceinline__ ushort4 mix4(float4 cur, float4 prev, float4 m) {
    ushort4 o;
    o.x = f2bf(cur.x * m.x + prev.x * (1.f - m.x));
    o.y = f2bf(cur.y * m.y + prev.y * (1.f - m.y));
    o.z = f2bf(cur.z * m.z + prev.z * (1.f - m.z));
    o.w = f2bf(cur.w * m.w + prev.w * (1.f - m.w));
    return o;
}

__global__ __launch_bounds__(256) void mix3(const float* __restrict__ rx,
                                            const float* __restrict__ sh,
                                            const float* __restrict__ mk,
                                            const float* __restrict__ mv,
                                            const float* __restrict__ mr,
                                            u16* __restrict__ xk,
                                            u16* __restrict__ xv,
                                            u16* __restrict__ xr) {
    const int i4 = blockIdx.x * 256 + threadIdx.x;     // one float4 per thread
    const int t = i4 >> 9, c4 = i4 & 511;
    float4 cur = ((const float4*)rx)[i4];
    float4 prev = (t == 0) ? ((const float4*)sh)[c4] : ((const float4*)rx)[i4 - 512];
    ((ushort4*)xk)[i4] = mix4(cur, prev, ((const float4*)mk)[c4]);
    ((ushort4*)xv)[i4] = mix4(cur, prev, ((const float4*)mv)[c4]);
    ((ushort4*)xr)[i4] = mix4(cur, prev, ((const float4*)mr)[c4]);
}

__global__ __launch_bounds__(256) void mix2(const float* __restrict__ rx,
                                            const float* __restrict__ sh,
                                            const float* __restrict__ mk,
                                            const float* __restrict__ mr,
                                            u16* __restrict__ fk,
                                            u16* __restrict__ fr) {
    const int i4 = blockIdx.x * 256 + threadIdx.x;
    const int t = i4 >> 9, c4 = i4 & 511;
    float4 cur = ((const float4*)rx)[i4];
    float4 prev = (t == 0) ? ((const float4*)sh)[c4] : ((const float4*)rx)[i4 - 512];
    ((ushort4*)fk)[i4] = mix4(cur, prev, ((const float4*)mk)[c4]);
    ((ushort4*)fr)[i4] = mix4(cur, prev, ((const float4*)mr)[c4]);
}

// ---------- f32 -> bf16 conversion (8 elems/thread/iter) ----------
__global__ __launch_bounds__(256) void cvt_bf16(const float* __restrict__ in,
                                                u16* __restrict__ out, int n8) {
    int i = blockIdx.x * 256 + threadIdx.x;
    const int stride = gridDim.x * 256;
    for (; i < n8; i += stride) {
        const float4* p = (const float4*)(in + (size_t)i * 8);
        float4 a = p[0], b = p[1];
        ushort4 lo, hi;
        lo.x = f2bf(a.x); lo.y = f2bf(a.y); lo.z = f2bf(a.z); lo.w = f2bf(a.w);
        hi.x = f2bf(b.x); hi.y = f2bf(b.y); hi.z = f2bf(b.z); hi.w = f2bf(b.w);
        ((ushort4*)out)[i * 2] = lo;
        ((ushort4*)out)[i * 2 + 1] = hi;
    }
}

// ---------- WKV sequential scan (one thread per channel) ----------
__global__ __launch_bounds__(256) void wkv_scan(const float* __restrict__ td,
                                                const float* __restrict__ tf,
                                                const float* __restrict__ k,
                                                const float* __restrict__ v,
                                                const float* __restrict__ r,
                                                const float* __restrict__ st,
                                                u16* __restrict__ p) {
    const int c = blockIdx.x * 256 + threadIdx.x;       // 0..2047
    const float u = tf[c];
    const float w = -expf(td[c]);
    const float ew = expf(w);
    float a = st[c];
    float b = st[C_DIM + c];
    size_t o = c;
    for (int t = 0; t < T_DIM; ++t, o += C_DIM) {
        const float kt = k[o], vt = v[o], rt = r[o];
        const float e = expf(u + w + kt);
        const float y = (a + e * vt) / (b + e);
        const float kk = expf(kt);
        a = (a + kk * vt) * ew;
        b = (b + kk) * ew;
        const float sr = 1.f / (1.f + expf(-rt));
        p[o] = f2bf(sr * y);
    }
}

// ---------- bf16 NT GEMM: out[m,n] = sum_k A[m,k]*B[n,k] ----------
// 128x128 tile, BK=64, 4 waves (each 64x64), global_load_lds staging.
enum { EPI_F32 = 0, EPI_ADDX = 1, EPI_RELU2 = 2, EPI_SIGMULADD = 3 };

template <int EPI>
__global__ __launch_bounds__(256) void gemm_bt(const u16* __restrict__ A,
                                               const u16* __restrict__ B,
                                               int M, int N, int K,
                                               void* __restrict__ outp,
                                               const float* __restrict__ aux1,
                                               const float* __restrict__ aux2) {
    __shared__ u16 As[128 * 64];
    __shared__ u16 Bs[128 * 64];
    const int tid = threadIdx.x;
    const int lane = tid & 63, wid = tid >> 6;
    const int wr = wid >> 1, wc = wid & 1;          // 2x2 waves of 64x64
    const int bm = blockIdx.y, bn = blockIdx.x;

    const u16* Ag = A + (size_t)bm * 128 * K;
    const u16* Bg = B + (size_t)bn * 128 * K;

    const f32x4 fz = {0.f, 0.f, 0.f, 0.f};
    f32x4 acc[4][4];
    #pragma unroll
    for (int m = 0; m < 4; ++m)
        #pragma unroll
        for (int n = 0; n < 4; ++n) acc[m][n] = fz;

    const int nk = K >> 6;
    for (int kt = 0; kt < nk; ++kt) {
        const u16* Agk = Ag + (kt << 6);
        const u16* Bgk = Bg + (kt << 6);
        #pragma unroll
        for (int i = 0; i < 4; ++i) {
            const int id = i * 256 + tid;
            async16(Agk + (size_t)(id >> 3) * K + ((id & 7) << 3), &As[(i * 4 + wid) << 9]);
        }
        #pragma unroll
        for (int i = 0; i < 4; ++i) {
            const int id = i * 256 + tid;
            async16(Bgk + (size_t)(id >> 3) * K + ((id & 7) << 3), &Bs[(i * 4 + wid) << 9]);
        }
        __syncthreads();
        #pragma unroll
        for (int kk = 0; kk < 2; ++kk) {
            const int ko = (kk << 5) + ((lane >> 4) << 3);
            bf16x8 af[4], bfr[4];
            #pragma unroll
            for (int m = 0; m < 4; ++m)
                af[m] = *(const bf16x8*)&As[((wr << 6) + (m << 4) + (lane & 15)) * 64 + ko];
            #pragma unroll
            for (int n = 0; n < 4; ++n)
                bfr[n] = *(const bf16x8*)&Bs[((wc << 6) + (n << 4) + (lane & 15)) * 64 + ko];
            #pragma unroll
            for (int m = 0; m < 4; ++m)
                #pragma unroll
                for (int n = 0; n < 4; ++n)
                    acc[m][n] = __builtin_amdgcn_mfma_f32_16x16x32_bf16(af[m], bfr[n], acc[m][n], 0, 0, 0);
        }
        __syncthreads();
    }

    const int r0 = bm * 128 + (wr << 6) + ((lane >> 4) << 2);
    const int c0 = bn * 128 + (wc << 6) + (lane & 15);
    #pragma unroll
    for (int m = 0; m < 4; ++m) {
        #pragma unroll
        for (int n = 0; n < 4; ++n) {
            #pragma unroll
            for (int j = 0; j < 4; ++j) {
                const int rr = r0 + (m << 4) + j;
                const int cc = c0 + (n << 4);
                const size_t o = (size_t)rr * N + cc;
                const float val = acc[m][n][j];
                if constexpr (EPI == EPI_F32) {
                    ((float*)outp)[o] = val;
                } else if constexpr (EPI == EPI_ADDX) {
                    ((float*)outp)[o] = aux1[o] + val;
                } else if constexpr (EPI == EPI_RELU2) {
                    const float tpos = fmaxf(val, 0.f);
                    ((u16*)outp)[o] = f2bf(tpos * tpos);
                } else {
                    const float sg = 1.f / (1.f + expf(-val));
                    ((float*)outp)[o] = aux1[o] + sg * aux2[o];
                }
            }
        }
    }
}

// ---------- launcher ----------
extern "C" void kernel_launch(void* const* d_in, const int* in_sizes, int n_in,
                              void* d_out, int out_size, void* d_ws, size_t ws_size,
                              hipStream_t stream) {
    const float* x         = (const float*)d_in[0];
    const float* att_shift = (const float*)d_in[1];
    const float* wkv_state = (const float*)d_in[2];
    const float* ffn_shift = (const float*)d_in[3];
    const float* ln1w = (const float*)d_in[4];
    const float* ln1b = (const float*)d_in[5];
    const float* ln2w = (const float*)d_in[6];
    const float* ln2b = (const float*)d_in[7];
    const float* tmk  = (const float*)d_in[8];
    const float* tmv  = (const float*)d_in[9];
    const float* tmr  = (const float*)d_in[10];
    const float* td   = (const float*)d_in[11];
    const float* tf   = (const float*)d_in[12];
    const float* Wk   = (const float*)d_in[13];
    const float* Wv   = (const float*)d_in[14];
    const float* Wr   = (const float*)d_in[15];
    const float* Wo   = (const float*)d_in[16];
    const float* ftmk = (const float*)d_in[17];
    const float* ftmr = (const float*)d_in[18];
    const float* Wfk  = (const float*)d_in[19];   // [F, C]
    const float* Wfv  = (const float*)d_in[20];   // [C, F]
    const float* Wfr  = (const float*)d_in[21];   // [C, C]
    float* out = (float*)d_out;

    char* ws = (char*)d_ws;
    const size_t MB = 1ull << 20;
    float* rx  = (float*)(ws + 0);            // 16 MB f32 [T,C]  (also fx)
    u16*   xk  = (u16*)(ws + 16 * MB);        // 8 MB bf16       (also fk)
    u16*   xv  = (u16*)(ws + 24 * MB);        // 8 MB bf16       (also fr)
    u16*   xr  = (u16*)(ws + 32 * MB);        // 8 MB bf16
    float* kb  = (float*)(ws + 40 * MB);      // 16 MB f32
    float* vb  = (float*)(ws + 56 * MB);      // 16 MB f32
    float* rb  = (float*)(ws + 72 * MB);      // 16 MB f32        (also kv)
    u16*   pb  = (u16*)(ws + 88 * MB);        // 8 MB bf16
    float* x1  = (float*)(ws + 96 * MB);      // 16 MB f32
    u16*   kf  = (u16*)(ws + 112 * MB);       // 32 MB bf16 [T,F]
    u16*   Wb  = (u16*)(ws + 144 * MB);       // 32 MB bf16 weight scratch
    // total: 176 MB

    const int T = T_DIM, C = C_DIM, F = F_DIM;
    const dim3 blk(256);
    const dim3 gCC(C / 128, T / 128);   // 16x16
    const dim3 gCF(F / 128, T / 128);   // 64x16

    // --- TimeMix ---
    ln_row<<<T, blk, 0, stream>>>(x, ln1w, ln1b, rx);
    mix3<<<(T * C / 4) / 256, blk, 0, stream>>>(rx, att_shift, tmk, tmv, tmr, xk, xv, xr);

    cvt_bf16<<<2048, blk, 0, stream>>>(Wk, Wb, C * C / 8);
    gemm_bt<EPI_F32><<<gCC, blk, 0, stream>>>(xk, Wb, T, C, C, kb, nullptr, nullptr);
    cvt_bf16<<<2048, blk, 0, stream>>>(Wv, Wb, C * C / 8);
    gemm_bt<EPI_F32><<<gCC, blk, 0, stream>>>(xv, Wb, T, C, C, vb, nullptr, nullptr);
    cvt_bf16<<<2048, blk, 0, stream>>>(Wr, Wb, C * C / 8);
    gemm_bt<EPI_F32><<<gCC, blk, 0, stream>>>(xr, Wb, T, C, C, rb, nullptr, nullptr);

    wkv_scan<<<C / 256, blk, 0, stream>>>(td, tf, kb, vb, rb, wkv_state, pb);

    cvt_bf16<<<2048, blk, 0, stream>>>(Wo, Wb, C * C / 8);
    gemm_bt<EPI_ADDX><<<gCC, blk, 0, stream>>>(pb, Wb, T, C, C, x1, x, nullptr);

    // --- ChannelMix ---
    ln_row<<<T, blk, 0, stream>>>(x1, ln2w, ln2b, rx);
    mix2<<<(T * C / 4) / 256, blk, 0, stream>>>(rx, ffn_shift, ftmk, ftmr, xk, xv);

    cvt_bf16<<<2048, blk, 0, stream>>>(Wfk, Wb, F * C / 8);
    gemm_bt<EPI_RELU2><<<gCF, blk, 0, stream>>>(xk, Wb, T, F, C, kf, nullptr, nullptr);
    cvt_bf16<<<2048, blk, 0, stream>>>(Wfv, Wb, C * F / 8);
    gemm_bt<EPI_F32><<<gCC, blk, 0, stream>>>(kf, Wb, T, C, F, rb, nullptr, nullptr);
    cvt_bf16<<<2048, blk, 0, stream>>>(Wfr, Wb, C * C / 8);
    gemm_bt<EPI_SIGMULADD><<<gCC, blk, 0, stream>>>(xv, Wb, T, C, C, out, x1, rb);
}

// Round 2
// 626.911 us; speedup vs baseline: 2.0438x; 2.0438x over previous
//
#include <hip/hip_runtime.h>
#include <hip/hip_bf16.h>

typedef unsigned short u16;
typedef short bf16x8 __attribute__((ext_vector_type(8)));
typedef float f32x4 __attribute__((ext_vector_type(4)));

#define T_DIM 2048
#define C_DIM 2048
#define F_DIM 8192
#define WKV_L 32
#define WKV_P (T_DIM / WKV_L)   // 64 chunks

// ---------- helpers ----------
__device__ __forceinline__ u16 f2bf(float f) {
    unsigned int u = __float_as_uint(f);
    u += 0x7fff + ((u >> 16) & 1);          // round-to-nearest-even
    return (u16)(u >> 16);
}

__device__ __forceinline__ void async16(const void* g, void* l) {
    __builtin_amdgcn_global_load_lds(
        (__attribute__((address_space(1))) const unsigned int*)g,
        (__attribute__((address_space(3))) unsigned int*)l, 16, 0, 0);
}

// ---------- LayerNorm (one block per row, C=2048) ----------
__global__ __launch_bounds__(256) void ln_row(const float* __restrict__ x,
                                              const float* __restrict__ w,
                                              const float* __restrict__ b,
                                              float* __restrict__ out) {
    __shared__ float red[8];
    const int t = blockIdx.x, tid = threadIdx.x;
    const float4* xr = (const float4*)(x + (size_t)t * C_DIM);
    float4 a0 = xr[tid * 2], a1 = xr[tid * 2 + 1];
    float s = a0.x + a0.y + a0.z + a0.w + a1.x + a1.y + a1.z + a1.w;
    float q = a0.x * a0.x + a0.y * a0.y + a0.z * a0.z + a0.w * a0.w
            + a1.x * a1.x + a1.y * a1.y + a1.z * a1.z + a1.w * a1.w;
    #pragma unroll
    for (int off = 32; off > 0; off >>= 1) {
        s += __shfl_down(s, off);
        q += __shfl_down(q, off);
    }
    const int lane = tid & 63, wv = tid >> 6;
    if (lane == 0) { red[wv] = s; red[4 + wv] = q; }
    __syncthreads();
    if (tid == 0) {
        red[0] = red[0] + red[1] + red[2] + red[3];
        red[4] = red[4] + red[5] + red[6] + red[7];
    }
    __syncthreads();
    s = red[0]; q = red[4];
    const float mean = s * (1.f / C_DIM);
    const float var = q * (1.f / C_DIM) - mean * mean;
    const float inv = rsqrtf(var + 1e-5f);
    const float4* w4 = (const float4*)w;
    const float4* b4 = (const float4*)b;
    float4* o4 = (float4*)(out + (size_t)t * C_DIM);
    #pragma unroll
    for (int j = 0; j < 2; ++j) {
        float4 xv = j ? a1 : a0;
        float4 wv4 = w4[tid * 2 + j], bv = b4[tid * 2 + j];
        float4 r;
        r.x = (xv.x - mean) * inv * wv4.x + bv.x;
        r.y = (xv.y - mean) * inv * wv4.y + bv.y;
        r.z = (xv.z - mean) * inv * wv4.z + bv.z;
        r.w = (xv.w - mean) * inv * wv4.w + bv.w;
        o4[tid * 2 + j] = r;
    }
}

// ---------- token-shift mixes ----------
__device__ __forceinline__ ushort4 mix4(float4 cur, float4 prev, float4 m) {
    ushort4 o;
    o.x = f2bf(cur.x * m.x + prev.x * (1.f - m.x));
    o.y = f2bf(cur.y * m.y + prev.y * (1.f - m.y));
    o.z = f2bf(cur.z * m.z + prev.z * (1.f - m.z));
    o.w = f2bf(cur.w * m.w + prev.w * (1.f - m.w));
    return o;
}

__global__ __launch_bounds__(256) void mix3(const float* __restrict__ rx,
                                            const float* __restrict__ sh,
                                            const float* __restrict__ mk,
                                            const float* __restrict__ mv,
                                            const float* __restrict__ mr,
                                            u16* __restrict__ xk,
                                            u16* __restrict__ xv,
                                            u16* __restrict__ xr) {
    const int i4 = blockIdx.x * 256 + threadIdx.x;     // one float4 per thread
    const int t = i4 >> 9, c4 = i4 & 511;
    float4 cur = ((const float4*)rx)[i4];
    float4 prev = (t == 0) ? ((const float4*)sh)[c4] : ((const float4*)rx)[i4 - 512];
    ((ushort4*)xk)[i4] = mix4(cur, prev, ((const float4*)mk)[c4]);
    ((ushort4*)xv)[i4] = mix4(cur, prev, ((const float4*)mv)[c4]);
    ((ushort4*)xr)[i4] = mix4(cur, prev, ((const float4*)mr)[c4]);
}

__global__ __launch_bounds__(256) void mix2(const float* __restrict__ rx,
                                            const float* __restrict__ sh,
                                            const float* __restrict__ mk,
                                            const float* __restrict__ mr,
                                            u16* __restrict__ fk,
                                            u16* __restrict__ fr) {
    const int i4 = blockIdx.x * 256 + threadIdx.x;
    const int t = i4 >> 9, c4 = i4 & 511;
    float4 cur = ((const float4*)rx)[i4];
    float4 prev = (t == 0) ? ((const float4*)sh)[c4] : ((const float4*)rx)[i4 - 512];
    ((ushort4*)fk)[i4] = mix4(cur, prev, ((const float4*)mk)[c4]);
    ((ushort4*)fr)[i4] = mix4(cur, prev, ((const float4*)mr)[c4]);
}

// ---------- f32 -> bf16 conversion (8 elems/thread/iter) ----------
__global__ __launch_bounds__(256) void cvt_bf16(const float* __restrict__ in,
                                                u16* __restrict__ out, int n8) {
    int i = blockIdx.x * 256 + threadIdx.x;
    const int stride = gridDim.x * 256;
    for (; i < n8; i += stride) {
        const float4* p = (const float4*)(in + (size_t)i * 8);
        float4 a = p[0], b = p[1];
        ushort4 lo, hi;
        lo.x = f2bf(a.x); lo.y = f2bf(a.y); lo.z = f2bf(a.z); lo.w = f2bf(a.w);
        hi.x = f2bf(b.x); hi.y = f2bf(b.y); hi.z = f2bf(b.z); hi.w = f2bf(b.w);
        ((ushort4*)out)[i * 2] = lo;
        ((ushort4*)out)[i * 2 + 1] = hi;
    }
}

// ---------- WKV parallel scan ----------
// Phase 1: per-(channel, chunk) local accumulation A,B over L steps.
__global__ __launch_bounds__(256) void wkv_part(const float* __restrict__ td,
                                                const float* __restrict__ k,
                                                const float* __restrict__ v,
                                                float* __restrict__ Ab,
                                                float* __restrict__ Bb) {
    const int idx = blockIdx.x * 256 + threadIdx.x;     // C*P threads
    const int c = idx & (C_DIM - 1);
    const int p = idx >> 11;
    const float ew = expf(-expf(td[c]));
    float A = 0.f, B = 0.f;
    size_t o = (size_t)(p * WKV_L) * C_DIM + c;
    #pragma unroll 4
    for (int i = 0; i < WKV_L; ++i, o += C_DIM) {
        const float kk = expf(k[o]);
        A = (A + kk * v[o]) * ew;
        B = (B + kk) * ew;
    }
    Ab[p * C_DIM + c] = A;
    Bb[p * C_DIM + c] = B;
}

// Phase 2: serial combine across chunks; store each chunk's INCOMING state.
__global__ __launch_bounds__(256) void wkv_comb(const float* __restrict__ td,
                                                const float* __restrict__ st,
                                                const float* __restrict__ Ab,
                                                const float* __restrict__ Bb,
                                                float* __restrict__ Sa,
                                                float* __restrict__ Sb) {
    const int c = blockIdx.x * 256 + threadIdx.x;       // C threads
    const float w = -expf(td[c]);
    const float dL = expf(w * (float)WKV_L);            // ew^L
    float a = st[c];
    float b = st[C_DIM + c];
    #pragma unroll 4
    for (int p = 0; p < WKV_P; ++p) {
        Sa[p * C_DIM + c] = a;
        Sb[p * C_DIM + c] = b;
        a = dL * a + Ab[p * C_DIM + c];
        b = dL * b + Bb[p * C_DIM + c];
    }
}

// Phase 3: replay each chunk from its incoming state, emit sigmoid(r)*y in bf16.
__global__ __launch_bounds__(256) void wkv_emit(const float* __restrict__ td,
                                                const float* __restrict__ tf,
                                                const float* __restrict__ k,
                                                const float* __restrict__ v,
                                                const float* __restrict__ r,
                                                const float* __restrict__ Sa,
                                                const float* __restrict__ Sb,
                                                u16* __restrict__ pout) {
    const int idx = blockIdx.x * 256 + threadIdx.x;     // C*P threads
    const int c = idx & (C_DIM - 1);
    const int p = idx >> 11;
    const float u = tf[c];
    const float w = -expf(td[c]);
    const float ew = expf(w);
    float a = Sa[p * C_DIM + c];
    float b = Sb[p * C_DIM + c];
    size_t o = (size_t)(p * WKV_L) * C_DIM + c;
    #pragma unroll 2
    for (int i = 0; i < WKV_L; ++i, o += C_DIM) {
        const float kt = k[o], vt = v[o], rt = r[o];
        const float e = expf(u + w + kt);
        const float y = (a + e * vt) / (b + e);
        const float kk = expf(kt);
        a = (a + kk * vt) * ew;
        b = (b + kk) * ew;
        const float sr = 1.f / (1.f + expf(-rt));
        pout[o] = f2bf(sr * y);
    }
}

// ---------- bf16 NT GEMM: out[m,n] = sum_k A[m,k]*B[n,k] ----------
// 128x128 tile, BK=64, 4 waves (each 64x64), global_load_lds staging.
enum { EPI_F32 = 0, EPI_ADDX = 1, EPI_RELU2 = 2, EPI_SIGMULADD = 3 };

template <int EPI>
__global__ __launch_bounds__(256) void gemm_bt(const u16* __restrict__ A,
                                               const u16* __restrict__ B,
                                               int M, int N, int K,
                                               void* __restrict__ outp,
                                               const float* __restrict__ aux1,
                                               const float* __restrict__ aux2) {
    __shared__ u16 As[128 * 64];
    __shared__ u16 Bs[128 * 64];
    const int tid = threadIdx.x;
    const int lane = tid & 63, wid = tid >> 6;
    const int wr = wid >> 1, wc = wid & 1;          // 2x2 waves of 64x64
    const int bm = blockIdx.y, bn = blockIdx.x;

    const u16* Ag = A + (size_t)bm * 128 * K;
    const u16* Bg = B + (size_t)bn * 128 * K;

    const f32x4 fz = {0.f, 0.f, 0.f, 0.f};
    f32x4 acc[4][4];
    #pragma unroll
    for (int m = 0; m < 4; ++m)
        #pragma unroll
        for (int n = 0; n < 4; ++n) acc[m][n] = fz;

    const int nk = K >> 6;
    for (int kt = 0; kt < nk; ++kt) {
        const u16* Agk = Ag + (kt << 6);
        const u16* Bgk = Bg + (kt << 6);
        #pragma unroll
        for (int i = 0; i < 4; ++i) {
            const int id = i * 256 + tid;
            async16(Agk + (size_t)(id >> 3) * K + ((id & 7) << 3), &As[(i * 4 + wid) << 9]);
        }
        #pragma unroll
        for (int i = 0; i < 4; ++i) {
            const int id = i * 256 + tid;
            async16(Bgk + (size_t)(id >> 3) * K + ((id & 7) << 3), &Bs[(i * 4 + wid) << 9]);
        }
        __syncthreads();
        #pragma unroll
        for (int kk = 0; kk < 2; ++kk) {
            const int ko = (kk << 5) + ((lane >> 4) << 3);
            bf16x8 af[4], bfr[4];
            #pragma unroll
            for (int m = 0; m < 4; ++m)
                af[m] = *(const bf16x8*)&As[((wr << 6) + (m << 4) + (lane & 15)) * 64 + ko];
            #pragma unroll
            for (int n = 0; n < 4; ++n)
                bfr[n] = *(const bf16x8*)&Bs[((wc << 6) + (n << 4) + (lane & 15)) * 64 + ko];
            #pragma unroll
            for (int m = 0; m < 4; ++m)
                #pragma unroll
                for (int n = 0; n < 4; ++n)
                    acc[m][n] = __builtin_amdgcn_mfma_f32_16x16x32_bf16(af[m], bfr[n], acc[m][n], 0, 0, 0);
        }
        __syncthreads();
    }

    const int r0 = bm * 128 + (wr << 6) + ((lane >> 4) << 2);
    const int c0 = bn * 128 + (wc << 6) + (lane & 15);
    #pragma unroll
    for (int m = 0; m < 4; ++m) {
        #pragma unroll
        for (int n = 0; n < 4; ++n) {
            #pragma unroll
            for (int j = 0; j < 4; ++j) {
                const int rr = r0 + (m << 4) + j;
                const int cc = c0 + (n << 4);
                const size_t o = (size_t)rr * N + cc;
                const float val = acc[m][n][j];
                if constexpr (EPI == EPI_F32) {
                    ((float*)outp)[o] = val;
                } else if constexpr (EPI == EPI_ADDX) {
                    ((float*)outp)[o] = aux1[o] + val;
                } else if constexpr (EPI == EPI_RELU2) {
                    const float tpos = fmaxf(val, 0.f);
                    ((u16*)outp)[o] = f2bf(tpos * tpos);
                } else {
                    const float sg = 1.f / (1.f + expf(-val));
                    ((float*)outp)[o] = aux1[o] + sg * aux2[o];
                }
            }
        }
    }
}

// ---------- launcher ----------
extern "C" void kernel_launch(void* const* d_in, const int* in_sizes, int n_in,
                              void* d_out, int out_size, void* d_ws, size_t ws_size,
                              hipStream_t stream) {
    const float* x         = (const float*)d_in[0];
    const float* att_shift = (const float*)d_in[1];
    const float* wkv_state = (const float*)d_in[2];
    const float* ffn_shift = (const float*)d_in[3];
    const float* ln1w = (const float*)d_in[4];
    const float* ln1b = (const float*)d_in[5];
    const float* ln2w = (const float*)d_in[6];
    const float* ln2b = (const float*)d_in[7];
    const float* tmk  = (const float*)d_in[8];
    const float* tmv  = (const float*)d_in[9];
    const float* tmr  = (const float*)d_in[10];
    const float* td   = (const float*)d_in[11];
    const float* tf   = (const float*)d_in[12];
    const float* Wk   = (const float*)d_in[13];
    const float* Wv   = (const float*)d_in[14];
    const float* Wr   = (const float*)d_in[15];
    const float* Wo   = (const float*)d_in[16];
    const float* ftmk = (const float*)d_in[17];
    const float* ftmr = (const float*)d_in[18];
    const float* Wfk  = (const float*)d_in[19];   // [F, C]
    const float* Wfv  = (const float*)d_in[20];   // [C, F]
    const float* Wfr  = (const float*)d_in[21];   // [C, C]
    float* out = (float*)d_out;

    char* ws = (char*)d_ws;
    const size_t MB = 1ull << 20;
    float* rx  = (float*)(ws + 0);            // 16 MB f32 [T,C]  (also fx)
    u16*   xk  = (u16*)(ws + 16 * MB);        // 8 MB bf16       (also fk)
    u16*   xv  = (u16*)(ws + 24 * MB);        // 8 MB bf16       (also fr)
    u16*   xr  = (u16*)(ws + 32 * MB);        // 8 MB bf16
    float* kb  = (float*)(ws + 40 * MB);      // 16 MB f32
    float* vb  = (float*)(ws + 56 * MB);      // 16 MB f32
    float* rb  = (float*)(ws + 72 * MB);      // 16 MB f32        (also kv)
    u16*   pb  = (u16*)(ws + 88 * MB);        // 8 MB bf16
    float* x1  = (float*)(ws + 96 * MB);      // 16 MB f32
    u16*   kf  = (u16*)(ws + 112 * MB);       // 32 MB bf16 [T,F]
    u16*   Wb  = (u16*)(ws + 144 * MB);       // 32 MB bf16 weight scratch
    // total: 176 MB
    // wkv scan scratch overlays the kf region (dead during TimeMix):
    float* wAb = (float*)(ws + 112 * MB);               // 512 KB [P][C]
    float* wBb = (float*)(ws + 112 * MB + 512 * 1024);  // 512 KB
    float* wSa = (float*)(ws + 113 * MB);               // 512 KB
    float* wSb = (float*)(ws + 113 * MB + 512 * 1024);  // 512 KB

    const int T = T_DIM, C = C_DIM, F = F_DIM;
    const dim3 blk(256);
    const dim3 gCC(C / 128, T / 128);   // 16x16
    const dim3 gCF(F / 128, T / 128);   // 64x16

    // --- TimeMix ---
    ln_row<<<T, blk, 0, stream>>>(x, ln1w, ln1b, rx);
    mix3<<<(T * C / 4) / 256, blk, 0, stream>>>(rx, att_shift, tmk, tmv, tmr, xk, xv, xr);

    cvt_bf16<<<2048, blk, 0, stream>>>(Wk, Wb, C * C / 8);
    gemm_bt<EPI_F32><<<gCC, blk, 0, stream>>>(xk, Wb, T, C, C, kb, nullptr, nullptr);
    cvt_bf16<<<2048, blk, 0, stream>>>(Wv, Wb, C * C / 8);
    gemm_bt<EPI_F32><<<gCC, blk, 0, stream>>>(xv, Wb, T, C, C, vb, nullptr, nullptr);
    cvt_bf16<<<2048, blk, 0, stream>>>(Wr, Wb, C * C / 8);
    gemm_bt<EPI_F32><<<gCC, blk, 0, stream>>>(xr, Wb, T, C, C, rb, nullptr, nullptr);

    // parallel WKV: chunked scan (P=64 chunks of L=32)
    wkv_part<<<(C * WKV_P) / 256, blk, 0, stream>>>(td, kb, vb, wAb, wBb);
    wkv_comb<<<C / 256, blk, 0, stream>>>(td, wkv_state, wAb, wBb, wSa, wSb);
    wkv_emit<<<(C * WKV_P) / 256, blk, 0, stream>>>(td, tf, kb, vb, rb, wSa, wSb, pb);

    cvt_bf16<<<2048, blk, 0, stream>>>(Wo, Wb, C * C / 8);
    gemm_bt<EPI_ADDX><<<gCC, blk, 0, stream>>>(pb, Wb, T, C, C, x1, x, nullptr);

    // --- ChannelMix ---
    ln_row<<<T, blk, 0, stream>>>(x1, ln2w, ln2b, rx);
    mix2<<<(T * C / 4) / 256, blk, 0, stream>>>(rx, ffn_shift, ftmk, ftmr, xk, xv);

    cvt_bf16<<<2048, blk, 0, stream>>>(Wfk, Wb, F * C / 8);
    gemm_bt<EPI_RELU2><<<gCF, blk, 0, stream>>>(xk, Wb, T, F, C, kf, nullptr, nullptr);
    cvt_bf16<<<2048, blk, 0, stream>>>(Wfv, Wb, C * F / 8);
    gemm_bt<EPI_F32><<<gCC, blk, 0, stream>>>(kf, Wb, T, C, F, rb, nullptr, nullptr);
    cvt_bf16<<<2048, blk, 0, stream>>>(Wfr, Wb, C * C / 8);
    gemm_bt<EPI_SIGMULADD><<<gCC, blk, 0, stream>>>(xv, Wb, T, C, C, out, x1, rb);
}

// Round 3
// 464.582 us; speedup vs baseline: 2.7579x; 1.3494x over previous
//
#include <hip/hip_runtime.h>
#include <hip/hip_bf16.h>

typedef unsigned short u16;
typedef short bf16x8 __attribute__((ext_vector_type(8)));
typedef float f32x4 __attribute__((ext_vector_type(4)));

#define T_DIM 2048
#define C_DIM 2048
#define F_DIM 8192
#define WKV_L 32
#define WKV_P (T_DIM / WKV_L)   // 64 chunks

// ---------- helpers ----------
__device__ __forceinline__ u16 f2bf(float f) {
    unsigned int u = __float_as_uint(f);
    u += 0x7fff + ((u >> 16) & 1);          // round-to-nearest-even
    return (u16)(u >> 16);
}

__device__ __forceinline__ void async16(const void* g, void* l) {
    __builtin_amdgcn_global_load_lds(
        (__attribute__((address_space(1))) const unsigned int*)g,
        (__attribute__((address_space(3))) unsigned int*)l, 16, 0, 0);
}

// ---------- LayerNorm (one block per row, C=2048) ----------
__global__ __launch_bounds__(256) void ln_row(const float* __restrict__ x,
                                              const float* __restrict__ w,
                                              const float* __restrict__ b,
                                              float* __restrict__ out) {
    __shared__ float red[8];
    const int t = blockIdx.x, tid = threadIdx.x;
    const float4* xr = (const float4*)(x + (size_t)t * C_DIM);
    float4 a0 = xr[tid * 2], a1 = xr[tid * 2 + 1];
    float s = a0.x + a0.y + a0.z + a0.w + a1.x + a1.y + a1.z + a1.w;
    float q = a0.x * a0.x + a0.y * a0.y + a0.z * a0.z + a0.w * a0.w
            + a1.x * a1.x + a1.y * a1.y + a1.z * a1.z + a1.w * a1.w;
    #pragma unroll
    for (int off = 32; off > 0; off >>= 1) {
        s += __shfl_down(s, off);
        q += __shfl_down(q, off);
    }
    const int lane = tid & 63, wv = tid >> 6;
    if (lane == 0) { red[wv] = s; red[4 + wv] = q; }
    __syncthreads();
    if (tid == 0) {
        red[0] = red[0] + red[1] + red[2] + red[3];
        red[4] = red[4] + red[5] + red[6] + red[7];
    }
    __syncthreads();
    s = red[0]; q = red[4];
    const float mean = s * (1.f / C_DIM);
    const float var = q * (1.f / C_DIM) - mean * mean;
    const float inv = rsqrtf(var + 1e-5f);
    const float4* w4 = (const float4*)w;
    const float4* b4 = (const float4*)b;
    float4* o4 = (float4*)(out + (size_t)t * C_DIM);
    #pragma unroll
    for (int j = 0; j < 2; ++j) {
        float4 xv = j ? a1 : a0;
        float4 wv4 = w4[tid * 2 + j], bv = b4[tid * 2 + j];
        float4 r;
        r.x = (xv.x - mean) * inv * wv4.x + bv.x;
        r.y = (xv.y - mean) * inv * wv4.y + bv.y;
        r.z = (xv.z - mean) * inv * wv4.z + bv.z;
        r.w = (xv.w - mean) * inv * wv4.w + bv.w;
        o4[tid * 2 + j] = r;
    }
}

// ---------- token-shift mixes ----------
__device__ __forceinline__ ushort4 mix4(float4 cur, float4 prev, float4 m) {
    ushort4 o;
    o.x = f2bf(cur.x * m.x + prev.x * (1.f - m.x));
    o.y = f2bf(cur.y * m.y + prev.y * (1.f - m.y));
    o.z = f2bf(cur.z * m.z + prev.z * (1.f - m.z));
    o.w = f2bf(cur.w * m.w + prev.w * (1.f - m.w));
    return o;
}

__global__ __launch_bounds__(256) void mix3(const float* __restrict__ rx,
                                            const float* __restrict__ sh,
                                            const float* __restrict__ mk,
                                            const float* __restrict__ mv,
                                            const float* __restrict__ mr,
                                            u16* __restrict__ xk,
                                            u16* __restrict__ xv,
                                            u16* __restrict__ xr) {
    const int i4 = blockIdx.x * 256 + threadIdx.x;     // one float4 per thread
    const int t = i4 >> 9, c4 = i4 & 511;
    float4 cur = ((const float4*)rx)[i4];
    float4 prev = (t == 0) ? ((const float4*)sh)[c4] : ((const float4*)rx)[i4 - 512];
    ((ushort4*)xk)[i4] = mix4(cur, prev, ((const float4*)mk)[c4]);
    ((ushort4*)xv)[i4] = mix4(cur, prev, ((const float4*)mv)[c4]);
    ((ushort4*)xr)[i4] = mix4(cur, prev, ((const float4*)mr)[c4]);
}

__global__ __launch_bounds__(256) void mix2(const float* __restrict__ rx,
                                            const float* __restrict__ sh,
                                            const float* __restrict__ mk,
                                            const float* __restrict__ mr,
                                            u16* __restrict__ fk,
                                            u16* __restrict__ fr) {
    const int i4 = blockIdx.x * 256 + threadIdx.x;
    const int t = i4 >> 9, c4 = i4 & 511;
    float4 cur = ((const float4*)rx)[i4];
    float4 prev = (t == 0) ? ((const float4*)sh)[c4] : ((const float4*)rx)[i4 - 512];
    ((ushort4*)fk)[i4] = mix4(cur, prev, ((const float4*)mk)[c4]);
    ((ushort4*)fr)[i4] = mix4(cur, prev, ((const float4*)mr)[c4]);
}

// ---------- f32 -> bf16 conversion ----------
__global__ __launch_bounds__(256) void cvt_bf16(const float* __restrict__ in,
                                                u16* __restrict__ out, int n8) {
    int i = blockIdx.x * 256 + threadIdx.x;
    const int stride = gridDim.x * 256;
    for (; i < n8; i += stride) {
        const float4* p = (const float4*)(in + (size_t)i * 8);
        float4 a = p[0], b = p[1];
        ushort4 lo, hi;
        lo.x = f2bf(a.x); lo.y = f2bf(a.y); lo.z = f2bf(a.z); lo.w = f2bf(a.w);
        hi.x = f2bf(b.x); hi.y = f2bf(b.y); hi.z = f2bf(b.z); hi.w = f2bf(b.w);
        ((ushort4*)out)[i * 2] = lo;
        ((ushort4*)out)[i * 2 + 1] = hi;
    }
}

// ---------- 4-way partial-sum reduce (float4) ----------
__global__ __launch_bounds__(256) void reduce4(const float* __restrict__ p0,
                                               const float* __restrict__ p1,
                                               const float* __restrict__ p2,
                                               const float* __restrict__ p3,
                                               float* __restrict__ o, int n4) {
    int i = blockIdx.x * 256 + threadIdx.x;
    const int stride = gridDim.x * 256;
    for (; i < n4; i += stride) {
        float4 a = ((const float4*)p0)[i], b = ((const float4*)p1)[i];
        float4 c = ((const float4*)p2)[i], d = ((const float4*)p3)[i];
        float4 r;
        r.x = a.x + b.x + c.x + d.x;
        r.y = a.y + b.y + c.y + d.y;
        r.z = a.z + b.z + c.z + d.z;
        r.w = a.w + b.w + c.w + d.w;
        ((float4*)o)[i] = r;
    }
}

// ---------- WKV parallel scan ----------
__global__ __launch_bounds__(256) void wkv_part(const float* __restrict__ td,
                                                const float* __restrict__ k,
                                                const float* __restrict__ v,
                                                float* __restrict__ Ab,
                                                float* __restrict__ Bb) {
    const int idx = blockIdx.x * 256 + threadIdx.x;     // C*P threads
    const int c = idx & (C_DIM - 1);
    const int p = idx >> 11;
    const float ew = expf(-expf(td[c]));
    float A = 0.f, B = 0.f;
    size_t o = (size_t)(p * WKV_L) * C_DIM + c;
    #pragma unroll 4
    for (int i = 0; i < WKV_L; ++i, o += C_DIM) {
        const float kk = expf(k[o]);
        A = (A + kk * v[o]) * ew;
        B = (B + kk) * ew;
    }
    Ab[p * C_DIM + c] = A;
    Bb[p * C_DIM + c] = B;
}

__global__ __launch_bounds__(256) void wkv_comb(const float* __restrict__ td,
                                                const float* __restrict__ st,
                                                const float* __restrict__ Ab,
                                                const float* __restrict__ Bb,
                                                float* __restrict__ Sa,
                                                float* __restrict__ Sb) {
    const int c = blockIdx.x * 256 + threadIdx.x;       // C threads
    const float w = -expf(td[c]);
    const float dL = expf(w * (float)WKV_L);            // ew^L
    float a = st[c];
    float b = st[C_DIM + c];
    #pragma unroll 4
    for (int p = 0; p < WKV_P; ++p) {
        Sa[p * C_DIM + c] = a;
        Sb[p * C_DIM + c] = b;
        a = dL * a + Ab[p * C_DIM + c];
        b = dL * b + Bb[p * C_DIM + c];
    }
}

__global__ __launch_bounds__(256) void wkv_emit(const float* __restrict__ td,
                                                const float* __restrict__ tf,
                                                const float* __restrict__ k,
                                                const float* __restrict__ v,
                                                const float* __restrict__ r,
                                                const float* __restrict__ Sa,
                                                const float* __restrict__ Sb,
                                                u16* __restrict__ pout) {
    const int idx = blockIdx.x * 256 + threadIdx.x;     // C*P threads
    const int c = idx & (C_DIM - 1);
    const int p = idx >> 11;
    const float u = tf[c];
    const float w = -expf(td[c]);
    const float ew = expf(w);
    float a = Sa[p * C_DIM + c];
    float b = Sb[p * C_DIM + c];
    size_t o = (size_t)(p * WKV_L) * C_DIM + c;
    #pragma unroll 2
    for (int i = 0; i < WKV_L; ++i, o += C_DIM) {
        const float kt = k[o], vt = v[o], rt = r[o];
        const float e = expf(u + w + kt);
        const float y = (a + e * vt) / (b + e);
        const float kk = expf(kt);
        a = (a + kk * vt) * ew;
        b = (b + kk) * ew;
        const float sr = 1.f / (1.f + expf(-rt));
        pout[o] = f2bf(sr * y);
    }
}

// ---------- 256x256 bf16 NT GEMM, 4-slot pipelined, counted vmcnt ----------
// out[m,n] = sum_k A[m,k]*B[n,k].  BM=BN=256, BK=32. 512 thr = 8 waves (2Mx4N),
// per-wave 128x64 out (8m x 4n frags of 16x16). LDS: 4 slots x (A 16KB + B 16KB)
// = 128 KiB. st_16x32 swizzle: pre-swizzled global source, swizzled ds_read.
// Slot timeline: tile t staged at iter t-3 (after barrier => prior reader done);
// vmcnt(8) at iter t => tiles <= t landed (t+1, t+2 in flight, never drained).
enum { EPI_F32 = 0, EPI_ADDX = 1, EPI_RELU2 = 2, EPI_SIGMULADD = 3 };

template <int EPI>
__global__ __launch_bounds__(512, 2) void gemm256(
        const u16* __restrict__ A, int lda, long a_zs,
        const u16* __restrict__ B, int ldb, long b_zs,
        int Kloop,
        void* __restrict__ outp, int ldo, long o_zs,
        const float* __restrict__ aux1, const float* __restrict__ aux2) {
    __shared__ u16 lds[4 * 16384];   // 128 KiB
    const int tid = threadIdx.x;
    const int l = tid & 63, w = tid >> 6;
    const int wr = w >> 2, wcn = w & 3;
    const int bm = blockIdx.y, bn = blockIdx.x, z = blockIdx.z;

    const u16* Ag = A + (size_t)z * a_zs + (size_t)bm * 256 * lda;
    const u16* Bg = B + (size_t)z * b_zs + (size_t)bn * 256 * ldb;

    // --- staging addresses (pre-swizzled global source, linear LDS dest) ---
    // LDS region byte off for thread (w,l), load j: off = j*8192 + w*1024 + l*16
    // linear elem (row, colbyte); source colbyte ^= 32 if bit9(off) (st_16x32).
    long gA[2], gB[2];
    int dA[2], dB[2];
    #pragma unroll
    for (int j = 0; j < 2; ++j) {
        const int off = j * 8192 + w * 1024 + l * 16;
        const int row = off >> 6;
        const int cb = (off & 63) ^ (((off >> 9) & 1) << 5);
        gA[j] = (long)row * lda + (cb >> 1);
        gB[j] = (long)row * ldb + (cb >> 1);
        dA[j] = j * 4096 + w * 512;            // element index (wave-uniform)
        dB[j] = 8192 + j * 4096 + w * 512;
    }

    // --- ds_read fragment offsets (swizzled), element index within slot ---
    int offA[8], offB[4];
    #pragma unroll
    for (int m = 0; m < 8; ++m) {
        const int lin = (wr * 128 + m * 16 + (l & 15)) * 64 + ((l >> 4) << 4);
        offA[m] = (lin ^ (((lin >> 9) & 1) << 5)) >> 1;
    }
    #pragma unroll
    for (int n = 0; n < 4; ++n) {
        const int lin = (wcn * 64 + n * 16 + (l & 15)) * 64 + ((l >> 4) << 4);
        offB[n] = 8192 + ((lin ^ (((lin >> 9) & 1) << 5)) >> 1);
    }

    const f32x4 fz = {0.f, 0.f, 0.f, 0.f};
    f32x4 acc[8][4];
    #pragma unroll
    for (int m = 0; m < 8; ++m)
        #pragma unroll
        for (int n = 0; n < 4; ++n) acc[m][n] = fz;

    const int NT = Kloop >> 5;

    auto stage = [&](int kt, int sp) {
        const long ko = (long)kt << 5;
        const int sb = sp * 16384;
        async16(Ag + gA[0] + ko, &lds[sb + dA[0]]);
        async16(Ag + gA[1] + ko, &lds[sb + dA[1]]);
        async16(Bg + gB[0] + ko, &lds[sb + dB[0]]);
        async16(Bg + gB[1] + ko, &lds[sb + dB[1]]);
    };

    // prologue: tiles 0,1,2 -> slots 0,1,2 (12 loads outstanding)
    stage(0, 0);
    stage(1, 1);
    stage(2, 2);

    for (int t = 0; t < NT; ++t) {
        // tiles <= t landed; t+1, t+2 stay in flight (counted, never drain-0)
        asm volatile("s_waitcnt vmcnt(8)" ::: "memory");
        __builtin_amdgcn_s_barrier();
        __builtin_amdgcn_sched_barrier(0);
        // stage tile t+3 into slot (t+3)&3 (clamped re-stage at tail: harmless,
        // keeps vmcnt counts uniform; lands in a slot with no future readers)
        {
            const int tp = (t + 3 < NT) ? t + 3 : NT - 1;
            stage(tp, (t + 3) & 3);
        }
        const int sb = (t & 3) * 16384;
        bf16x8 af[8], bfv[4];
        #pragma unroll
        for (int m = 0; m < 8; ++m) af[m] = *(const bf16x8*)&lds[sb + offA[m]];
        #pragma unroll
        for (int n = 0; n < 4; ++n) bfv[n] = *(const bf16x8*)&lds[sb + offB[n]];
        __builtin_amdgcn_s_setprio(1);
        #pragma unroll
        for (int m = 0; m < 4; ++m)
            #pragma unroll
            for (int n = 0; n < 4; ++n)
                acc[m][n] = __builtin_amdgcn_mfma_f32_16x16x32_bf16(af[m], bfv[n], acc[m][n], 0, 0, 0);
        __builtin_amdgcn_s_setprio(0);
        __builtin_amdgcn_s_setprio(1);
        #pragma unroll
        for (int m = 4; m < 8; ++m)
            #pragma unroll
            for (int n = 0; n < 4; ++n)
                acc[m][n] = __builtin_amdgcn_mfma_f32_16x16x32_bf16(af[m], bfv[n], acc[m][n], 0, 0, 0);
        __builtin_amdgcn_s_setprio(0);
    }
    asm volatile("s_waitcnt vmcnt(0)" ::: "memory");  // drain tail stages

    // --- epilogue ---
    const int r00 = bm * 256 + wr * 128 + ((l >> 4) << 2);
    const int c00 = bn * 256 + wcn * 64 + (l & 15);
    #pragma unroll
    for (int m = 0; m < 8; ++m) {
        #pragma unroll
        for (int n = 0; n < 4; ++n) {
            #pragma unroll
            for (int j = 0; j < 4; ++j) {
                const int rr = r00 + m * 16 + j;
                const int cc = c00 + n * 16;
                const size_t o = (size_t)rr * ldo + cc;
                const float val = acc[m][n][j];
                if constexpr (EPI == EPI_F32) {
                    ((float*)outp)[(size_t)z * o_zs + o] = val;
                } else if constexpr (EPI == EPI_ADDX) {
                    ((float*)outp)[o] = aux1[o] + val;
                } else if constexpr (EPI == EPI_RELU2) {
                    const float tp = fmaxf(val, 0.f);
                    ((u16*)outp)[o] = f2bf(tp * tp);
                } else {
                    const float sg = 1.f / (1.f + expf(-val));
                    ((float*)outp)[o] = aux1[o] + sg * aux2[o];
                }
            }
        }
    }
}

// ---------- launcher ----------
extern "C" void kernel_launch(void* const* d_in, const int* in_sizes, int n_in,
                              void* d_out, int out_size, void* d_ws, size_t ws_size,
                              hipStream_t stream) {
    const float* x         = (const float*)d_in[0];
    const float* att_shift = (const float*)d_in[1];
    const float* wkv_state = (const float*)d_in[2];
    const float* ffn_shift = (const float*)d_in[3];
    const float* ln1w = (const float*)d_in[4];
    const float* ln1b = (const float*)d_in[5];
    const float* ln2w = (const float*)d_in[6];
    const float* ln2b = (const float*)d_in[7];
    const float* tmk  = (const float*)d_in[8];
    const float* tmv  = (const float*)d_in[9];
    const float* tmr  = (const float*)d_in[10];
    const float* td   = (const float*)d_in[11];
    const float* tf   = (const float*)d_in[12];
    const float* Wk   = (const float*)d_in[13];
    const float* Wv   = (const float*)d_in[14];
    const float* Wr   = (const float*)d_in[15];
    const float* Wo   = (const float*)d_in[16];
    const float* ftmk = (const float*)d_in[17];
    const float* ftmr = (const float*)d_in[18];
    const float* Wfk  = (const float*)d_in[19];   // [F, C]
    const float* Wfv  = (const float*)d_in[20];   // [C, F]
    const float* Wfr  = (const float*)d_in[21];   // [C, C]
    float* out = (float*)d_out;

    char* ws = (char*)d_ws;
    const size_t MB = 1ull << 20;
    float* rx  = (float*)(ws + 0);            // 16 MB f32 [T,C]  (fx; later kv-reduced)
    u16*   xk  = (u16*)(ws + 16 * MB);        // 8 MB bf16       (also fk)
    u16*   xv  = (u16*)(ws + 24 * MB);        // 8 MB bf16       (also fr)
    u16*   xr  = (u16*)(ws + 32 * MB);        // 8 MB bf16
    float* kb  = (float*)(ws + 40 * MB);      // 16 MB f32
    float* vb  = (float*)(ws + 56 * MB);      // 16 MB f32
    float* rb  = (float*)(ws + 72 * MB);      // 16 MB f32
    u16*   pb  = (u16*)(ws + 88 * MB);        // 8 MB bf16
    float* x1  = (float*)(ws + 96 * MB);      // 16 MB f32
    u16*   kf  = (u16*)(ws + 112 * MB);       // 32 MB bf16 [T,F]
    u16*   Wb  = (u16*)(ws + 144 * MB);       // 32 MB bf16 weight scratch
    // wkv scratch overlays kf region (dead during TimeMix):
    float* wAb = (float*)(ws + 112 * MB);
    float* wBb = (float*)(ws + 112 * MB + 512 * 1024);
    float* wSa = (float*)(ws + 113 * MB);
    float* wSb = (float*)(ws + 113 * MB + 512 * 1024);
    // split-K partials for ffn_value: 4 x 16 MB, uniform stride, in regions
    // dead at that point ([32,96) = xr,kb,vb,rb,pb after wkv/att done)
    float* fvp = (float*)(ws + 32 * MB);      // partials at 32,48,64,80 MB

    const int T = T_DIM, C = C_DIM, F = F_DIM;
    const dim3 blk(256), blk5(512);

    // --- TimeMix ---
    ln_row<<<T, blk, 0, stream>>>(x, ln1w, ln1b, rx);
    mix3<<<(T * C / 4) / 256, blk, 0, stream>>>(rx, att_shift, tmk, tmv, tmr, xk, xv, xr);

    cvt_bf16<<<2048, blk, 0, stream>>>(Wk, Wb, C * C / 8);
    cvt_bf16<<<2048, blk, 0, stream>>>(Wv, Wb + (size_t)C * C, C * C / 8);
    cvt_bf16<<<2048, blk, 0, stream>>>(Wr, Wb + 2 * (size_t)C * C, C * C / 8);
    // batched qkv: z=0,1,2 -> (xk,xv,xr) x (Wk,Wv,Wr) -> (kb,vb,rb)
    gemm256<EPI_F32><<<dim3(C / 256, T / 256, 3), blk5, 0, stream>>>(
        xk, C, (long)T * C, Wb, C, (long)C * C, C, kb, C, (long)T * C, nullptr, nullptr);

    wkv_part<<<(C * WKV_P) / 256, blk, 0, stream>>>(td, kb, vb, wAb, wBb);
    wkv_comb<<<C / 256, blk, 0, stream>>>(td, wkv_state, wAb, wBb, wSa, wSb);
    wkv_emit<<<(C * WKV_P) / 256, blk, 0, stream>>>(td, tf, kb, vb, rb, wSa, wSb, pb);

    cvt_bf16<<<2048, blk, 0, stream>>>(Wo, Wb, C * C / 8);
    gemm256<EPI_ADDX><<<dim3(C / 256, T / 256, 1), blk5, 0, stream>>>(
        pb, C, 0, Wb, C, 0, C, x1, C, 0, x, nullptr);

    // --- ChannelMix ---
    ln_row<<<T, blk, 0, stream>>>(x1, ln2w, ln2b, rx);
    mix2<<<(T * C / 4) / 256, blk, 0, stream>>>(rx, ffn_shift, ftmk, ftmr, xk, xv);

    cvt_bf16<<<2048, blk, 0, stream>>>(Wfk, Wb, F * C / 8);
    gemm256<EPI_RELU2><<<dim3(F / 256, T / 256, 1), blk5, 0, stream>>>(
        xk, C, 0, Wb, C, 0, C, kf, F, 0, nullptr, nullptr);

    cvt_bf16<<<2048, blk, 0, stream>>>(Wfv, Wb, C * F / 8);
    // split-K x4 over K=8192: z-chunk offset 2048 in A and B rows
    gemm256<EPI_F32><<<dim3(C / 256, T / 256, 4), blk5, 0, stream>>>(
        kf, F, 2048, Wb, F, 2048, 2048, fvp, C, (long)T * C, nullptr, nullptr);
    reduce4<<<2048, blk, 0, stream>>>(fvp, fvp + (size_t)T * C, fvp + 2 * (size_t)T * C,
                                      fvp + 3 * (size_t)T * C, rx, T * C / 4);

    cvt_bf16<<<2048, blk, 0, stream>>>(Wfr, Wb, C * C / 8);
    gemm256<EPI_SIGMULADD><<<dim3(C / 256, T / 256, 1), blk5, 0, stream>>>(
        xv, C, 0, Wb, C, 0, C, out, C, 0, x1, rx);
}